// Round 6
// baseline (925.456 us; speedup 1.0000x reference)
//
#include <hip/hip_runtime.h>

#define T_PTS 100000
#define NB 2
#define GCELLS 32768
#define NCELL (NB * GCELLS)
#define HID 128
#define MBLK 64
#define RBPB 1563                /* ceil(100000/64) */
#define GRID_RB (NB * RBPB)

typedef __attribute__((ext_vector_type(8))) short bf16x8;
typedef __attribute__((ext_vector_type(4))) float f32x4;

#define MFMA16 __builtin_amdgcn_mfma_f32_16x16x32_bf16

__device__ __forceinline__ unsigned short bf16rne(float f) {
  unsigned u = __float_as_uint(f);
  return (unsigned short)((u + 0x7FFFu + ((u >> 16) & 1u)) >> 16);
}
// pack fp32 -> (bf16 hi << 16) | bf16 lo   (x ~= hi + lo, ~2^-17 rel)
__device__ __forceinline__ unsigned packhl(float f) {
  unsigned short h = bf16rne(f);
  float hf = __uint_as_float(((unsigned)h) << 16);
  unsigned short l = bf16rne(f - hf);
  return (((unsigned)h) << 16) | (unsigned)l;
}

union U8 { bf16x8 v; unsigned u[4]; };

// ---------------------------------------------------------------------------
// Fused resnet block. 64 points/block, 4 waves, each wave 64 rows x 32 cols.
// net / cell are PACKED (h,l) u32.
// Register software-pipeline (issue order = consume order):
//   preload B1(0); per ks: issue B2(ks), issue A(ks+1) -> pass1 on B1(ks)
//   -> issue B1(ks+1) -> pass2 on B2(ks) -> store A(ks+1) -> barrier.
// ---------------------------------------------------------------------------
template <int MODE>
__global__ __launch_bounds__(256, 4) void resblock_mfma(
    const void* __restrict__ srcv, const float* __restrict__ posw,
    const float* __restrict__ posb, const unsigned* __restrict__ cell,
    const int* __restrict__ idx, const unsigned short* __restrict__ w0p,
    const float* __restrict__ b0, const unsigned short* __restrict__ w1p,
    const float* __restrict__ b1, const unsigned short* __restrict__ swp,
    unsigned* __restrict__ net_out) {
  __shared__ unsigned short lds[16384];
  const int tid = threadIdx.x;
  const int lane = tid & 63;
  const int wc = tid >> 6;
  const int b = blockIdx.x / RBPB;
  const int t0 = (blockIdx.x % RBPB) * MBLK;
  const int valid = (T_PTS - t0 < MBLK) ? (T_PTS - t0) : MBLK;

  // staging coords: 4 threads per point-row, 8 u32 each
  const int pt = tid >> 2;
  const int kc = (tid & 3) << 3;
  const int lstore = ((tid & 3) * 16 + (pt & 15)) ^ (tid & 3);  // l ^ ((l>>4)&3)
  const int sbase0 = (pt >> 4) * 512 + lstore * 8;
  const bool pv = (pt < valid);

  const unsigned* nrow = nullptr;
  const unsigned* crow = nullptr;
  float pp0 = 0.f, pp1 = 0.f, pp2 = 0.f;
  if (MODE == 1) {
    if (pv) {
      const long prow = (long)b * T_PTS + t0 + pt;
      nrow = (const unsigned*)srcv + prow * HID;
      crow = cell + ((long)b * GCELLS + idx[prow]) * HID;
    }
  } else {
    if (pv) {
      const float* ppp = (const float*)srcv + ((long)b * T_PTS + t0 + pt) * 3;
      pp0 = ppp[0]; pp1 = ppp[1]; pp2 = ppp[2];
    }
  }

  auto load_x = [&](int ks, unsigned* w) {
    if (MODE == 1) {
      if (pv) {
        const unsigned* rp = (ks < 4) ? (nrow + ks * 32 + kc)
                                      : (crow + (ks - 4) * 32 + kc);
        uint4 a = *(const uint4*)rp;
        uint4 c = *(const uint4*)(rp + 4);
        w[0] = a.x; w[1] = a.y; w[2] = a.z; w[3] = a.w;
        w[4] = c.x; w[5] = c.y; w[6] = c.z; w[7] = c.w;
      } else {
#pragma unroll
        for (int i = 0; i < 8; ++i) w[i] = 0u;
      }
    } else {
      const int kb = ks * 32 + kc;
      float xv[8];
#pragma unroll
      for (int i = 0; i < 8; i += 4) {
        float4 wa = *(const float4*)(posw + kb + i);
        float4 wb = *(const float4*)(posw + 256 + kb + i);
        float4 wcc = *(const float4*)(posw + 512 + kb + i);
        float4 bb = *(const float4*)(posb + kb + i);
        xv[i + 0] = fmaf(pp0, wa.x, fmaf(pp1, wb.x, fmaf(pp2, wcc.x, bb.x)));
        xv[i + 1] = fmaf(pp0, wa.y, fmaf(pp1, wb.y, fmaf(pp2, wcc.y, bb.y)));
        xv[i + 2] = fmaf(pp0, wa.z, fmaf(pp1, wb.z, fmaf(pp2, wcc.z, bb.z)));
        xv[i + 3] = fmaf(pp0, wa.w, fmaf(pp1, wb.w, fmaf(pp2, wcc.w, bb.w)));
      }
#pragma unroll
      for (int i = 0; i < 8; ++i) w[i] = pv ? packhl(xv[i]) : 0u;
    }
  };

  auto store_x = [&](int ks, const unsigned* w) {
    const int base = ((ks & 1) << 13) + sbase0;
    U8 vh, vl, vrh, vrl;
#pragma unroll
    for (int p = 0; p < 4; ++p) {
      const unsigned w0 = w[2 * p], w1 = w[2 * p + 1];
      const unsigned r0 = ((int)w0 < 0) ? 0u : w0;
      const unsigned r1 = ((int)w1 < 0) ? 0u : w1;
      vh.u[p] = __builtin_amdgcn_perm(w1, w0, 0x07060302u);
      vl.u[p] = __builtin_amdgcn_perm(w1, w0, 0x05040100u);
      vrh.u[p] = __builtin_amdgcn_perm(r1, r0, 0x07060302u);
      vrl.u[p] = __builtin_amdgcn_perm(r1, r0, 0x05040100u);
    }
    *(bf16x8*)(lds + base) = vh.v;
    *(bf16x8*)(lds + base + 2048) = vl.v;
    *(bf16x8*)(lds + base + 4096) = vrh.v;
    *(bf16x8*)(lds + base + 6144) = vrl.v;
  };

  // load one pass's B frags (2 nt, hi+lo planes)
  auto load_B = [&](const unsigned short* base, int loOff, int ks, bf16x8* h,
                    bf16x8* l) {
#pragma unroll
    for (int nt = 0; nt < 2; ++nt) {
      const int fi = (ks * 8 + wc * 2 + nt) * 512 + lane * 8;
      h[nt] = *(const bf16x8*)(base + fi);
      l[nt] = *(const bf16x8*)(base + loOff + fi);
    }
  };

  f32x4 accy[4][2], acco[4][2];
#pragma unroll
  for (int i = 0; i < 4; ++i)
#pragma unroll
    for (int j = 0; j < 2; ++j) {
      f32x4 z = {0.f, 0.f, 0.f, 0.f};
      accy[i][j] = z;
      acco[i][j] = z;
    }

  bf16x8 b1h[2], b1l[2];
  load_B(w0p, 32768, 0, b1h, b1l);  // B for pass1(ks=0)
  {
    unsigned w[8];
    load_x(0, w);
    store_x(0, w);
  }
  __syncthreads();

  const int lar = lane ^ ((lane >> 4) & 3);
#pragma unroll 1
  for (int ks = 0; ks < 8; ++ks) {
    bf16x8 b2h[2], b2l[2];
    load_B(swp, 32768, ks, b2h, b2l);  // issue B for pass2(ks)
    unsigned nxt[8];
    if (ks < 7) load_x(ks + 1, nxt);   // issue A prefetch
    const int sb = (ks & 1) << 13;
    // pass 1: accy += relu(x) @ w0   (B already resident)
    __builtin_amdgcn_s_setprio(1);
#pragma unroll
    for (int mt = 0; mt < 4; ++mt) {
      const int ab = sb + mt * 512 + lar * 8;
      bf16x8 arh = *(const bf16x8*)(lds + ab + 4096);
      bf16x8 arl = *(const bf16x8*)(lds + ab + 6144);
#pragma unroll
      for (int nt = 0; nt < 2; ++nt) {
        accy[mt][nt] = MFMA16(arh, b1h[nt], accy[mt][nt], 0, 0, 0);
        accy[mt][nt] = MFMA16(arh, b1l[nt], accy[mt][nt], 0, 0, 0);
        accy[mt][nt] = MFMA16(arl, b1h[nt], accy[mt][nt], 0, 0, 0);
      }
    }
    __builtin_amdgcn_s_setprio(0);
    if (ks < 7) load_B(w0p, 32768, ks + 1, b1h, b1l);  // issue B pass1(ks+1)
    // pass 2: acco += x @ sw   (covered by pass1 MFMAs)
    __builtin_amdgcn_s_setprio(1);
#pragma unroll
    for (int mt = 0; mt < 4; ++mt) {
      const int ab = sb + mt * 512 + lar * 8;
      bf16x8 axh = *(const bf16x8*)(lds + ab);
      bf16x8 axl = *(const bf16x8*)(lds + ab + 2048);
#pragma unroll
      for (int nt = 0; nt < 2; ++nt) {
        acco[mt][nt] = MFMA16(axh, b2h[nt], acco[mt][nt], 0, 0, 0);
        acco[mt][nt] = MFMA16(axh, b2l[nt], acco[mt][nt], 0, 0, 0);
        acco[mt][nt] = MFMA16(axl, b2h[nt], acco[mt][nt], 0, 0, 0);
      }
    }
    __builtin_amdgcn_s_setprio(0);
    if (ks < 7) store_x(ks + 1, nxt);
    __syncthreads();
  }

  // h = relu(y + b0) -> u16 hi/lo planes in LDS (aliases x buffers)
  {
    float b0v[2];
#pragma unroll
    for (int nt = 0; nt < 2; ++nt)
      b0v[nt] = b0[wc * 32 + nt * 16 + (lane & 15)];
#pragma unroll
    for (int mt = 0; mt < 4; ++mt) {
#pragma unroll
      for (int nt = 0; nt < 2; ++nt) {
        const int c = wc * 32 + nt * 16 + (lane & 15);
        const int k2 = c >> 5;
        const int j = c & 7;
        const int lahi = ((c & 31) >> 3) * 16;
#pragma unroll
        for (int r = 0; r < 4; ++r) {
          float h = fmaxf(accy[mt][nt][r] + b0v[nt], 0.f);
          unsigned short hh = bf16rne(h);
          float hf = __uint_as_float(((unsigned)hh) << 16);
          unsigned short hl = bf16rne(h - hf);
          int la = lahi + (lane >> 4) * 4 + r;
          la ^= (la >> 3) & 7;
          const int o = ((k2 * 4 + mt) * 64 + la) * 8 + j;
          lds[o] = hh;
          lds[o + 8192] = hl;
        }
      }
    }
  }
  __syncthreads();

  // GEMM2: acco += h @ w1  (B pipelined one k2 ahead)
  {
    const int lar2 = lane ^ ((lane >> 3) & 7);
    bf16x8 g2h[2], g2l[2];
    load_B(w1p, 16384, 0, g2h, g2l);
#pragma unroll
    for (int k2 = 0; k2 < 4; ++k2) {
      bf16x8 ch[2], cl[2];
#pragma unroll
      for (int nt = 0; nt < 2; ++nt) { ch[nt] = g2h[nt]; cl[nt] = g2l[nt]; }
      if (k2 < 3) load_B(w1p, 16384, k2 + 1, g2h, g2l);
      __builtin_amdgcn_s_setprio(1);
#pragma unroll
      for (int mt = 0; mt < 4; ++mt) {
        const int ab = ((k2 * 4 + mt) * 64 + lar2) * 8;
        bf16x8 ah = *(const bf16x8*)(lds + ab);
        bf16x8 al = *(const bf16x8*)(lds + ab + 8192);
#pragma unroll
        for (int nt = 0; nt < 2; ++nt) {
          acco[mt][nt] = MFMA16(ah, ch[nt], acco[mt][nt], 0, 0, 0);
          acco[mt][nt] = MFMA16(ah, cl[nt], acco[mt][nt], 0, 0, 0);
          acco[mt][nt] = MFMA16(al, ch[nt], acco[mt][nt], 0, 0, 0);
        }
      }
      __builtin_amdgcn_s_setprio(0);
    }
  }

  // epilogue: out = pack(acco + b1)
  {
    float b1v[2];
#pragma unroll
    for (int nt = 0; nt < 2; ++nt)
      b1v[nt] = b1[wc * 32 + nt * 16 + (lane & 15)];
#pragma unroll
    for (int mt = 0; mt < 4; ++mt) {
#pragma unroll
      for (int r = 0; r < 4; ++r) {
        const int row = mt * 16 + (lane >> 4) * 4 + r;
        if (row < valid) {
          unsigned* op = net_out + ((long)b * T_PTS + t0 + row) * HID;
          op[wc * 32 + (lane & 15)] = packhl(acco[mt][0][r] + b1v[0]);
          op[wc * 32 + 16 + (lane & 15)] = packhl(acco[mt][1][r] + b1v[1]);
        }
      }
    }
  }
}

// ---------------------------------------------------------------------------
// final: c = net @ fc_c_w + fc_c_b, fp32 written IN-PLACE over packed net.
// ---------------------------------------------------------------------------
__global__ __launch_bounds__(256, 4) void final_mfma(
    unsigned* __restrict__ net, const unsigned short* __restrict__ wcp,
    const float* __restrict__ bc) {
  __shared__ unsigned short lds[8192];
  const int tid = threadIdx.x;
  const int lane = tid & 63;
  const int wc = tid >> 6;
  const int b = blockIdx.x / RBPB;
  const int t0 = (blockIdx.x % RBPB) * MBLK;
  const int valid = (T_PTS - t0 < MBLK) ? (T_PTS - t0) : MBLK;

  const int pt = tid >> 2;
  const int kc = (tid & 3) << 3;
  const int lstore = ((tid & 3) * 16 + (pt & 15)) ^ (tid & 3);
  const int sbase0 = (pt >> 4) * 512 + lstore * 8;
  const bool pv = (pt < valid);
  const unsigned* nrow = pv ? net + ((long)b * T_PTS + t0 + pt) * HID : nullptr;

  auto load_x = [&](int ks, unsigned* w) {
    if (pv) {
      const unsigned* rp = nrow + ks * 32 + kc;
      uint4 a = *(const uint4*)rp;
      uint4 c = *(const uint4*)(rp + 4);
      w[0] = a.x; w[1] = a.y; w[2] = a.z; w[3] = a.w;
      w[4] = c.x; w[5] = c.y; w[6] = c.z; w[7] = c.w;
    } else {
#pragma unroll
      for (int i = 0; i < 8; ++i) w[i] = 0u;
    }
  };
  auto store_x = [&](int ks, const unsigned* w) {
    const int base = ((ks & 1) << 12) + sbase0;
    U8 vh, vl;
#pragma unroll
    for (int p = 0; p < 4; ++p) {
      const unsigned w0 = w[2 * p], w1 = w[2 * p + 1];
      vh.u[p] = __builtin_amdgcn_perm(w1, w0, 0x07060302u);
      vl.u[p] = __builtin_amdgcn_perm(w1, w0, 0x05040100u);
    }
    *(bf16x8*)(lds + base) = vh.v;
    *(bf16x8*)(lds + base + 2048) = vl.v;
  };
  auto load_B = [&](int ks, bf16x8* h, bf16x8* l) {
#pragma unroll
    for (int nt = 0; nt < 2; ++nt) {
      const int fi = (ks * 8 + wc * 2 + nt) * 512 + lane * 8;
      h[nt] = *(const bf16x8*)(wcp + fi);
      l[nt] = *(const bf16x8*)(wcp + 16384 + fi);
    }
  };

  f32x4 acc[4][2];
#pragma unroll
  for (int i = 0; i < 4; ++i)
#pragma unroll
    for (int j = 0; j < 2; ++j) {
      f32x4 z = {0.f, 0.f, 0.f, 0.f};
      acc[i][j] = z;
    }

  bf16x8 gh[2], gl[2];
  load_B(0, gh, gl);
  {
    unsigned w[8];
    load_x(0, w);
    store_x(0, w);
  }
  __syncthreads();

  const int lar = lane ^ ((lane >> 4) & 3);
#pragma unroll 1
  for (int ks = 0; ks < 4; ++ks) {
    unsigned nxt[8];
    if (ks < 3) load_x(ks + 1, nxt);
    bf16x8 ch[2], cl[2];
#pragma unroll
    for (int nt = 0; nt < 2; ++nt) { ch[nt] = gh[nt]; cl[nt] = gl[nt]; }
    if (ks < 3) load_B(ks + 1, gh, gl);
    const int sb = (ks & 1) << 12;
    __builtin_amdgcn_s_setprio(1);
#pragma unroll
    for (int mt = 0; mt < 4; ++mt) {
      const int ab = sb + mt * 512 + lar * 8;
      bf16x8 ah = *(const bf16x8*)(lds + ab);
      bf16x8 al = *(const bf16x8*)(lds + ab + 2048);
#pragma unroll
      for (int nt = 0; nt < 2; ++nt) {
        acc[mt][nt] = MFMA16(ah, ch[nt], acc[mt][nt], 0, 0, 0);
        acc[mt][nt] = MFMA16(ah, cl[nt], acc[mt][nt], 0, 0, 0);
        acc[mt][nt] = MFMA16(al, ch[nt], acc[mt][nt], 0, 0, 0);
      }
    }
    __builtin_amdgcn_s_setprio(0);
    if (ks < 3) store_x(ks + 1, nxt);
    __syncthreads();
  }

  float* fout = (float*)net;
  float bcv[2];
#pragma unroll
  for (int nt = 0; nt < 2; ++nt)
    bcv[nt] = bc[wc * 32 + nt * 16 + (lane & 15)];
#pragma unroll
  for (int mt = 0; mt < 4; ++mt) {
#pragma unroll
    for (int r = 0; r < 4; ++r) {
      const int row = mt * 16 + (lane >> 4) * 4 + r;
      if (row < valid) {
        float* op = fout + ((long)b * T_PTS + t0 + row) * HID;
        op[wc * 32 + (lane & 15)] = acc[mt][0][r] + bcv[0];
        op[wc * 32 + 16 + (lane & 15)] = acc[mt][1][r] + bcv[1];
      }
    }
  }
}

// ---------------------------------------------------------------------------
// one-time weight pack: fp32 (K,128) -> bf16 hi/lo planes in MFMA-B-frag order
// ---------------------------------------------------------------------------
__global__ void pack_weights(const float* __restrict__ fc0,
                             const float* __restrict__ fc1,
                             const float* __restrict__ sc,
                             const float* __restrict__ fcc,
                             unsigned short* __restrict__ w0p,
                             unsigned short* __restrict__ w1p,
                             unsigned short* __restrict__ swp,
                             unsigned short* __restrict__ wcp) {
  int gid = blockIdx.x * 256 + threadIdx.x;
  const float* src;
  unsigned short* dst;
  int K, e;
  if (gid < 163840) { src = fc0; dst = w0p; K = 256; e = gid; }
  else if (gid < 327680) { src = sc; dst = swp; K = 256; e = gid - 163840; }
  else if (gid < 409600) { src = fc1; dst = w1p; K = 128; e = gid - 327680; }
  else if (gid < 425984) { src = fcc; dst = wcp; K = 128; e = gid - 409600; }
  else return;
  const int mat = e / (K * 128);
  const int r = e - mat * K * 128;
  const int k = r >> 7, n = r & 127;
  const float x = src[e];
  const unsigned short hi = bf16rne(x);
  const float hf = __uint_as_float(((unsigned)hi) << 16);
  const unsigned short lo = bf16rne(x - hf);
  const int ks = k >> 5, lg = (k >> 3) & 3, j = k & 7;
  const int l = lg * 16 + (n & 15), nt = n >> 4;
  unsigned short* mb = dst + (long)mat * K * 256;
  const int off = ((ks * 8 + nt) * 64 + l) * 8 + j;
  mb[off] = hi;
  mb[off + K * 128] = lo;
}

// --------------------------- CSR build -------------------------------------
__global__ void zero_i32(int* __restrict__ p, int n) {
  const int i = blockIdx.x * 256 + threadIdx.x;
  if (i < n) p[i] = 0;
}

__global__ void count_csr(const int* __restrict__ idx, int* __restrict__ curs) {
  const int gid = blockIdx.x * 256 + threadIdx.x;
  if (gid >= NB * T_PTS) return;
  const int b = gid / T_PTS;
  atomicAdd(&curs[b * GCELLS + idx[gid]], 1);
}

__global__ __launch_bounds__(1024) void scan_csr(const int* __restrict__ cnt,
                                                 int* __restrict__ offsets) {
  __shared__ int part[1024];
  const int t = threadIdx.x;
  const int base = t * (NCELL / 1024);
  int s = 0;
  for (int i = 0; i < NCELL / 1024; ++i) s += cnt[base + i];
  part[t] = s;
  __syncthreads();
  for (int d = 1; d < 1024; d <<= 1) {
    int v = (t >= d) ? part[t - d] : 0;
    __syncthreads();
    part[t] += v;
    __syncthreads();
  }
  int run = (t == 0) ? 0 : part[t - 1];
  for (int i = 0; i < NCELL / 1024; ++i) {
    offsets[base + i] = run;
    run += cnt[base + i];
  }
  if (t == 1023) offsets[NCELL] = run;
}

__global__ void scatter_csr(const int* __restrict__ idx,
                            const int* __restrict__ offsets,
                            int* __restrict__ curs, int* __restrict__ perm) {
  const int gid = blockIdx.x * 256 + threadIdx.x;
  if (gid >= NB * T_PTS) return;
  const int b = gid / T_PTS;
  const int cellk = b * GCELLS + idx[gid];
  const int slot = offsets[cellk] + atomicAdd(&curs[cellk], 1);
  perm[slot] = gid;
}

// ------------------- CSR segmented reductions ------------------------------
__global__ __launch_bounds__(256) void pool_csr(const unsigned* __restrict__ net,
                                                const int* __restrict__ perm,
                                                const int* __restrict__ offsets,
                                                unsigned* __restrict__ cellf) {
  const int cellk = blockIdx.x * 4 + (threadIdx.x >> 6);
  const int lane = threadIdx.x & 63;
  const int s0 = offsets[cellk], s1 = offsets[cellk + 1];
  if (s0 >= s1) return;
  float m0 = -3.402823466e38f, m1 = -3.402823466e38f;
  unsigned b0 = 0u, b1 = 0u;
  for (int j = s0; j < s1; ++j) {
    const long row = perm[j];
    uint2 w = *(const uint2*)(net + row * HID + lane * 2);
    float v0 = __uint_as_float(w.x & 0xFFFF0000u) + __uint_as_float(w.x << 16);
    float v1 = __uint_as_float(w.y & 0xFFFF0000u) + __uint_as_float(w.y << 16);
    if (v0 > m0) { m0 = v0; b0 = w.x; }
    if (v1 > m1) { m1 = v1; b1 = w.y; }
  }
  uint2 o; o.x = b0; o.y = b1;
  *(uint2*)(cellf + (long)cellk * HID + lane * 2) = o;
}

__global__ __launch_bounds__(256) void cellsum_csr(
    const float* __restrict__ c, const int* __restrict__ perm,
    const int* __restrict__ offsets, float* __restrict__ sums) {
  const int cellk = blockIdx.x * 4 + (threadIdx.x >> 6);
  const int lane = threadIdx.x & 63;
  const int s0 = offsets[cellk], s1 = offsets[cellk + 1];
  if (s0 >= s1) return;
  float2 m = {0.f, 0.f};
  for (int j = s0; j < s1; ++j) {
    const long row = perm[j];
    float2 v = *(const float2*)(c + row * HID + lane * 2);
    m.x += v.x;
    m.y += v.y;
  }
  *(float2*)(sums + (long)cellk * HID + lane * 2) = m;
}

__global__ void mean_kernel(const float* __restrict__ sums,
                            const int* __restrict__ offsets,
                            float* __restrict__ out) {
  const long gid = (long)blockIdx.x * 256 + threadIdx.x;
  if (gid >= (long)NB * HID * GCELLS) return;
  const int g = (int)(gid % GCELLS);
  const int c = (int)((gid / GCELLS) % HID);
  const int b = (int)(gid / ((long)HID * GCELLS));
  const int cellk = b * GCELLS + g;
  const int cnt = offsets[cellk + 1] - offsets[cellk];
  out[gid] = cnt > 0 ? sums[(long)cellk * HID + c] / (float)cnt : 0.f;
}

extern "C" void kernel_launch(void* const* d_in, const int* in_sizes, int n_in,
                              void* d_out, int out_size, void* d_ws,
                              size_t ws_size, hipStream_t stream) {
  const float* points = (const float*)d_in[0];
  const int* idx = (const int*)d_in[1];
  const float* fc_pos_w = (const float*)d_in[2];
  const float* fc_pos_b = (const float*)d_in[3];
  const float* fc0_w = (const float*)d_in[4];
  const float* fc0_b = (const float*)d_in[5];
  const float* fc1_w = (const float*)d_in[6];
  const float* fc1_b = (const float*)d_in[7];
  const float* sc_w = (const float*)d_in[8];
  const float* fc_c_w = (const float*)d_in[9];
  const float* fc_c_b = (const float*)d_in[10];
  float* out = (float*)d_out;

  const long NET_BYTES = (long)NB * T_PTS * HID * 4;    // 102,400,000
  const long CELL_BYTES = (long)NB * GCELLS * HID * 4;  // 33,554,432
  unsigned* net = (unsigned*)d_ws;                       // packed (h,l)
  unsigned* cellf = (unsigned*)((char*)d_ws + NET_BYTES);
  float* sums = (float*)cellf;  // reused after last pooling
  int* offsets = (int*)((char*)d_ws + NET_BYTES + CELL_BYTES);  // 65537 ints

  // scratch in d_out's dead region (overwritten by mean_kernel at the end)
  unsigned short* packs = (unsigned short*)d_out;
  unsigned short* w0p = packs;            // 5 * 65536
  unsigned short* swp = packs + 327680;   // 5 * 65536
  unsigned short* w1p = packs + 655360;   // 5 * 32768
  unsigned short* wcp = packs + 819200;   // 32768
  int* curs = (int*)((char*)d_out + (2l << 20));
  int* perm = (int*)((char*)d_out + (3l << 20));

  const int GRID_PTS = (NB * T_PTS + 255) / 256;  // 782
  const int GRID_ZERO = (NCELL + 255) / 256;      // 256
  const int GRID_CELL = NCELL / 4;                // 16384
  const int GRID_MEAN = NB * HID * GCELLS / 256;  // 32768

  pack_weights<<<1664, 256, 0, stream>>>(fc0_w, fc1_w, sc_w, fc_c_w, w0p, w1p,
                                         swp, wcp);

  zero_i32<<<GRID_ZERO, 256, 0, stream>>>(curs, NCELL);
  count_csr<<<GRID_PTS, 256, 0, stream>>>(idx, curs);
  scan_csr<<<1, 1024, 0, stream>>>(curs, offsets);
  zero_i32<<<GRID_ZERO, 256, 0, stream>>>(curs, NCELL);
  scatter_csr<<<GRID_PTS, 256, 0, stream>>>(idx, offsets, curs, perm);

  resblock_mfma<0><<<GRID_RB, 256, 0, stream>>>(
      points, fc_pos_w, fc_pos_b, nullptr, nullptr, w0p, fc0_b, w1p, fc1_b,
      swp, net);

  for (int i = 1; i < 5; ++i) {
    pool_csr<<<GRID_CELL, 256, 0, stream>>>(net, perm, offsets, cellf);
    resblock_mfma<1><<<GRID_RB, 256, 0, stream>>>(
        net, nullptr, nullptr, cellf, idx, w0p + (long)i * 65536,
        fc0_b + i * HID, w1p + (long)i * 32768, fc1_b + i * HID,
        swp + (long)i * 65536, net);
  }

  final_mfma<<<GRID_RB, 256, 0, stream>>>(net, wcp, fc_c_b);
  cellsum_csr<<<GRID_CELL, 256, 0, stream>>>((const float*)net, perm, offsets,
                                             sums);
  mean_kernel<<<GRID_MEAN, 256, 0, stream>>>(sums, offsets, out);
}

// Round 7
// 776.371 us; speedup vs baseline: 1.1920x; 1.1920x over previous
//
#include <hip/hip_runtime.h>

#define T_PTS 100000
#define NB 2
#define GCELLS 32768
#define NCELL (NB * GCELLS)
#define HID 128
#define MBLK 64
#define RBPB 1563                /* ceil(100000/64) */
#define GRID_RB (NB * RBPB)

typedef __attribute__((ext_vector_type(8))) short bf16x8;
typedef __attribute__((ext_vector_type(4))) float f32x4;

#define MFMA16 __builtin_amdgcn_mfma_f32_16x16x32_bf16

__device__ __forceinline__ unsigned short bf16rne(float f) {
  unsigned u = __float_as_uint(f);
  return (unsigned short)((u + 0x7FFFu + ((u >> 16) & 1u)) >> 16);
}
// pack fp32 -> (bf16 hi << 16) | bf16 lo   (x ~= hi + lo, ~2^-17 rel)
__device__ __forceinline__ unsigned packhl(float f) {
  unsigned short h = bf16rne(f);
  float hf = __uint_as_float(((unsigned)h) << 16);
  unsigned short l = bf16rne(f - hf);
  return (((unsigned)h) << 16) | (unsigned)l;
}

union U8 { bf16x8 v; unsigned u[4]; };

// ---------------------------------------------------------------------------
// Fused resnet block. 64 points/block, 4 waves, each wave 64 rows x 32 cols.
// net / cell are PACKED (h,l) u32.
// Issue order per K-step = consume order: B1(w0), B2(sw), A(ks+1).
// vmcnt retires oldest-first -> pass1 waits only B1, pass2 waits only B2,
// A-prefetch rides through both MFMA passes and lands at store_x.
// launch_bounds (256,3): ~106 arch VGPRs available (64 AGPR accum), so the
// 40-reg in-flight set does NOT spill (R6 lesson: (256,4) spilled 568MB).
// ---------------------------------------------------------------------------
template <int MODE>
__global__ __launch_bounds__(256, 3) void resblock_mfma(
    const void* __restrict__ srcv, const float* __restrict__ posw,
    const float* __restrict__ posb, const unsigned* __restrict__ cell,
    const int* __restrict__ idx, const unsigned short* __restrict__ w0p,
    const float* __restrict__ b0, const unsigned short* __restrict__ w1p,
    const float* __restrict__ b1, const unsigned short* __restrict__ swp,
    unsigned* __restrict__ net_out) {
  __shared__ unsigned short lds[16384];
  const int tid = threadIdx.x;
  const int lane = tid & 63;
  const int wc = tid >> 6;
  const int b = blockIdx.x / RBPB;
  const int t0 = (blockIdx.x % RBPB) * MBLK;
  const int valid = (T_PTS - t0 < MBLK) ? (T_PTS - t0) : MBLK;

  // staging coords: 4 threads per point-row, 8 u32 each
  const int pt = tid >> 2;
  const int kc = (tid & 3) << 3;
  const int lstore = ((tid & 3) * 16 + (pt & 15)) ^ (tid & 3);  // l ^ ((l>>4)&3)
  const int sbase0 = (pt >> 4) * 512 + lstore * 8;
  const bool pv = (pt < valid);

  const unsigned* nrow = nullptr;
  const unsigned* crow = nullptr;
  float pp0 = 0.f, pp1 = 0.f, pp2 = 0.f;
  if (MODE == 1) {
    if (pv) {
      const long prow = (long)b * T_PTS + t0 + pt;
      nrow = (const unsigned*)srcv + prow * HID;
      crow = cell + ((long)b * GCELLS + idx[prow]) * HID;
    }
  } else {
    if (pv) {
      const float* ppp = (const float*)srcv + ((long)b * T_PTS + t0 + pt) * 3;
      pp0 = ppp[0]; pp1 = ppp[1]; pp2 = ppp[2];
    }
  }

  auto load_x = [&](int ks, unsigned* w) {
    if (MODE == 1) {
      if (pv) {
        const unsigned* rp = (ks < 4) ? (nrow + ks * 32 + kc)
                                      : (crow + (ks - 4) * 32 + kc);
        uint4 a = *(const uint4*)rp;
        uint4 c = *(const uint4*)(rp + 4);
        w[0] = a.x; w[1] = a.y; w[2] = a.z; w[3] = a.w;
        w[4] = c.x; w[5] = c.y; w[6] = c.z; w[7] = c.w;
      } else {
#pragma unroll
        for (int i = 0; i < 8; ++i) w[i] = 0u;
      }
    } else {
      const int kb = ks * 32 + kc;
      float xv[8];
#pragma unroll
      for (int i = 0; i < 8; i += 4) {
        float4 wa = *(const float4*)(posw + kb + i);
        float4 wb = *(const float4*)(posw + 256 + kb + i);
        float4 wcc = *(const float4*)(posw + 512 + kb + i);
        float4 bb = *(const float4*)(posb + kb + i);
        xv[i + 0] = fmaf(pp0, wa.x, fmaf(pp1, wb.x, fmaf(pp2, wcc.x, bb.x)));
        xv[i + 1] = fmaf(pp0, wa.y, fmaf(pp1, wb.y, fmaf(pp2, wcc.y, bb.y)));
        xv[i + 2] = fmaf(pp0, wa.z, fmaf(pp1, wb.z, fmaf(pp2, wcc.z, bb.z)));
        xv[i + 3] = fmaf(pp0, wa.w, fmaf(pp1, wb.w, fmaf(pp2, wcc.w, bb.w)));
      }
#pragma unroll
      for (int i = 0; i < 8; ++i) w[i] = pv ? packhl(xv[i]) : 0u;
    }
  };

  auto store_x = [&](int ks, const unsigned* w) {
    const int base = ((ks & 1) << 13) + sbase0;
    U8 vh, vl, vrh, vrl;
#pragma unroll
    for (int p = 0; p < 4; ++p) {
      const unsigned w0 = w[2 * p], w1 = w[2 * p + 1];
      const unsigned r0 = ((int)w0 < 0) ? 0u : w0;
      const unsigned r1 = ((int)w1 < 0) ? 0u : w1;
      vh.u[p] = __builtin_amdgcn_perm(w1, w0, 0x07060302u);
      vl.u[p] = __builtin_amdgcn_perm(w1, w0, 0x05040100u);
      vrh.u[p] = __builtin_amdgcn_perm(r1, r0, 0x07060302u);
      vrl.u[p] = __builtin_amdgcn_perm(r1, r0, 0x05040100u);
    }
    *(bf16x8*)(lds + base) = vh.v;
    *(bf16x8*)(lds + base + 2048) = vl.v;
    *(bf16x8*)(lds + base + 4096) = vrh.v;
    *(bf16x8*)(lds + base + 6144) = vrl.v;
  };

  // load one pass's B frags (2 nt, hi+lo planes)
  auto load_B = [&](const unsigned short* base, int loOff, int ks, bf16x8* h,
                    bf16x8* l) {
#pragma unroll
    for (int nt = 0; nt < 2; ++nt) {
      const int fi = (ks * 8 + wc * 2 + nt) * 512 + lane * 8;
      h[nt] = *(const bf16x8*)(base + fi);
      l[nt] = *(const bf16x8*)(base + loOff + fi);
    }
  };

  f32x4 accy[4][2], acco[4][2];
#pragma unroll
  for (int i = 0; i < 4; ++i)
#pragma unroll
    for (int j = 0; j < 2; ++j) {
      f32x4 z = {0.f, 0.f, 0.f, 0.f};
      accy[i][j] = z;
      acco[i][j] = z;
    }

  {
    unsigned w[8];
    load_x(0, w);
    store_x(0, w);
  }
  __syncthreads();

  const int lar = lane ^ ((lane >> 4) & 3);
#pragma unroll 1
  for (int ks = 0; ks < 8; ++ks) {
    // issue loads in consume order: B1, B2, A-prefetch
    bf16x8 b1h[2], b1l[2], b2h[2], b2l[2];
    load_B(w0p, 32768, ks, b1h, b1l);
    load_B(swp, 32768, ks, b2h, b2l);
    unsigned nxt[8];
    if (ks < 7) load_x(ks + 1, nxt);
    const int sb = (ks & 1) << 13;
    // pass 1: accy += relu(x) @ w0   (waits only on B1)
    __builtin_amdgcn_s_setprio(1);
#pragma unroll
    for (int mt = 0; mt < 4; ++mt) {
      const int ab = sb + mt * 512 + lar * 8;
      bf16x8 arh = *(const bf16x8*)(lds + ab + 4096);
      bf16x8 arl = *(const bf16x8*)(lds + ab + 6144);
#pragma unroll
      for (int nt = 0; nt < 2; ++nt) {
        accy[mt][nt] = MFMA16(arh, b1h[nt], accy[mt][nt], 0, 0, 0);
        accy[mt][nt] = MFMA16(arh, b1l[nt], accy[mt][nt], 0, 0, 0);
        accy[mt][nt] = MFMA16(arl, b1h[nt], accy[mt][nt], 0, 0, 0);
      }
    }
    __builtin_amdgcn_s_setprio(0);
    // pass 2: acco += x @ sw   (waits only on B2; A still in flight)
    __builtin_amdgcn_s_setprio(1);
#pragma unroll
    for (int mt = 0; mt < 4; ++mt) {
      const int ab = sb + mt * 512 + lar * 8;
      bf16x8 axh = *(const bf16x8*)(lds + ab);
      bf16x8 axl = *(const bf16x8*)(lds + ab + 2048);
#pragma unroll
      for (int nt = 0; nt < 2; ++nt) {
        acco[mt][nt] = MFMA16(axh, b2h[nt], acco[mt][nt], 0, 0, 0);
        acco[mt][nt] = MFMA16(axh, b2l[nt], acco[mt][nt], 0, 0, 0);
        acco[mt][nt] = MFMA16(axl, b2h[nt], acco[mt][nt], 0, 0, 0);
      }
    }
    __builtin_amdgcn_s_setprio(0);
    if (ks < 7) store_x(ks + 1, nxt);  // vmcnt(0) lands after 48 MFMAs
    __syncthreads();
  }

  // h = relu(y + b0) -> u16 hi/lo planes in LDS (aliases x buffers)
  {
    float b0v[2];
#pragma unroll
    for (int nt = 0; nt < 2; ++nt)
      b0v[nt] = b0[wc * 32 + nt * 16 + (lane & 15)];
#pragma unroll
    for (int mt = 0; mt < 4; ++mt) {
#pragma unroll
      for (int nt = 0; nt < 2; ++nt) {
        const int c = wc * 32 + nt * 16 + (lane & 15);
        const int k2 = c >> 5;
        const int j = c & 7;
        const int lahi = ((c & 31) >> 3) * 16;
#pragma unroll
        for (int r = 0; r < 4; ++r) {
          float h = fmaxf(accy[mt][nt][r] + b0v[nt], 0.f);
          unsigned short hh = bf16rne(h);
          float hf = __uint_as_float(((unsigned)hh) << 16);
          unsigned short hl = bf16rne(h - hf);
          int la = lahi + (lane >> 4) * 4 + r;
          la ^= (la >> 3) & 7;
          const int o = ((k2 * 4 + mt) * 64 + la) * 8 + j;
          lds[o] = hh;
          lds[o + 8192] = hl;
        }
      }
    }
  }
  __syncthreads();

  // GEMM2: acco += h @ w1  (B issued per k2, A already in LDS)
  {
    const int lar2 = lane ^ ((lane >> 3) & 7);
#pragma unroll
    for (int k2 = 0; k2 < 4; ++k2) {
      bf16x8 ch[2], cl[2];
      load_B(w1p, 16384, k2, ch, cl);
      __builtin_amdgcn_s_setprio(1);
#pragma unroll
      for (int mt = 0; mt < 4; ++mt) {
        const int ab = ((k2 * 4 + mt) * 64 + lar2) * 8;
        bf16x8 ah = *(const bf16x8*)(lds + ab);
        bf16x8 al = *(const bf16x8*)(lds + ab + 8192);
#pragma unroll
        for (int nt = 0; nt < 2; ++nt) {
          acco[mt][nt] = MFMA16(ah, ch[nt], acco[mt][nt], 0, 0, 0);
          acco[mt][nt] = MFMA16(ah, cl[nt], acco[mt][nt], 0, 0, 0);
          acco[mt][nt] = MFMA16(al, ch[nt], acco[mt][nt], 0, 0, 0);
        }
      }
      __builtin_amdgcn_s_setprio(0);
    }
  }

  // epilogue: out = pack(acco + b1)
  {
    float b1v[2];
#pragma unroll
    for (int nt = 0; nt < 2; ++nt)
      b1v[nt] = b1[wc * 32 + nt * 16 + (lane & 15)];
#pragma unroll
    for (int mt = 0; mt < 4; ++mt) {
#pragma unroll
      for (int r = 0; r < 4; ++r) {
        const int row = mt * 16 + (lane >> 4) * 4 + r;
        if (row < valid) {
          unsigned* op = net_out + ((long)b * T_PTS + t0 + row) * HID;
          op[wc * 32 + (lane & 15)] = packhl(acco[mt][0][r] + b1v[0]);
          op[wc * 32 + 16 + (lane & 15)] = packhl(acco[mt][1][r] + b1v[1]);
        }
      }
    }
  }
}

// ---------------------------------------------------------------------------
// final: c = net @ fc_c_w + fc_c_b, fp32 written IN-PLACE over packed net.
// Issue order per K-step: B(ks) then A(ks+1) -> pass waits vmcnt(2).
// ---------------------------------------------------------------------------
__global__ __launch_bounds__(256, 4) void final_mfma(
    unsigned* __restrict__ net, const unsigned short* __restrict__ wcp,
    const float* __restrict__ bc) {
  __shared__ unsigned short lds[8192];
  const int tid = threadIdx.x;
  const int lane = tid & 63;
  const int wc = tid >> 6;
  const int b = blockIdx.x / RBPB;
  const int t0 = (blockIdx.x % RBPB) * MBLK;
  const int valid = (T_PTS - t0 < MBLK) ? (T_PTS - t0) : MBLK;

  const int pt = tid >> 2;
  const int kc = (tid & 3) << 3;
  const int lstore = ((tid & 3) * 16 + (pt & 15)) ^ (tid & 3);
  const int sbase0 = (pt >> 4) * 512 + lstore * 8;
  const bool pv = (pt < valid);
  const unsigned* nrow = pv ? net + ((long)b * T_PTS + t0 + pt) * HID : nullptr;

  auto load_x = [&](int ks, unsigned* w) {
    if (pv) {
      const unsigned* rp = nrow + ks * 32 + kc;
      uint4 a = *(const uint4*)rp;
      uint4 c = *(const uint4*)(rp + 4);
      w[0] = a.x; w[1] = a.y; w[2] = a.z; w[3] = a.w;
      w[4] = c.x; w[5] = c.y; w[6] = c.z; w[7] = c.w;
    } else {
#pragma unroll
      for (int i = 0; i < 8; ++i) w[i] = 0u;
    }
  };
  auto store_x = [&](int ks, const unsigned* w) {
    const int base = ((ks & 1) << 12) + sbase0;
    U8 vh, vl;
#pragma unroll
    for (int p = 0; p < 4; ++p) {
      const unsigned w0 = w[2 * p], w1 = w[2 * p + 1];
      vh.u[p] = __builtin_amdgcn_perm(w1, w0, 0x07060302u);
      vl.u[p] = __builtin_amdgcn_perm(w1, w0, 0x05040100u);
    }
    *(bf16x8*)(lds + base) = vh.v;
    *(bf16x8*)(lds + base + 2048) = vl.v;
  };
  auto load_B = [&](int ks, bf16x8* h, bf16x8* l) {
#pragma unroll
    for (int nt = 0; nt < 2; ++nt) {
      const int fi = (ks * 8 + wc * 2 + nt) * 512 + lane * 8;
      h[nt] = *(const bf16x8*)(wcp + fi);
      l[nt] = *(const bf16x8*)(wcp + 16384 + fi);
    }
  };

  f32x4 acc[4][2];
#pragma unroll
  for (int i = 0; i < 4; ++i)
#pragma unroll
    for (int j = 0; j < 2; ++j) {
      f32x4 z = {0.f, 0.f, 0.f, 0.f};
      acc[i][j] = z;
    }

  {
    unsigned w[8];
    load_x(0, w);
    store_x(0, w);
  }
  __syncthreads();

  const int lar = lane ^ ((lane >> 4) & 3);
#pragma unroll 1
  for (int ks = 0; ks < 4; ++ks) {
    bf16x8 ch[2], cl[2];
    load_B(ks, ch, cl);           // B first (older)
    unsigned nxt[8];
    if (ks < 3) load_x(ks + 1, nxt);  // A second (younger, rides through)
    const int sb = (ks & 1) << 12;
    __builtin_amdgcn_s_setprio(1);
#pragma unroll
    for (int mt = 0; mt < 4; ++mt) {
      const int ab = sb + mt * 512 + lar * 8;
      bf16x8 ah = *(const bf16x8*)(lds + ab);
      bf16x8 al = *(const bf16x8*)(lds + ab + 2048);
#pragma unroll
      for (int nt = 0; nt < 2; ++nt) {
        acc[mt][nt] = MFMA16(ah, ch[nt], acc[mt][nt], 0, 0, 0);
        acc[mt][nt] = MFMA16(ah, cl[nt], acc[mt][nt], 0, 0, 0);
        acc[mt][nt] = MFMA16(al, ch[nt], acc[mt][nt], 0, 0, 0);
      }
    }
    __builtin_amdgcn_s_setprio(0);
    if (ks < 3) store_x(ks + 1, nxt);
    __syncthreads();
  }

  float* fout = (float*)net;
  float bcv[2];
#pragma unroll
  for (int nt = 0; nt < 2; ++nt)
    bcv[nt] = bc[wc * 32 + nt * 16 + (lane & 15)];
#pragma unroll
  for (int mt = 0; mt < 4; ++mt) {
#pragma unroll
    for (int r = 0; r < 4; ++r) {
      const int row = mt * 16 + (lane >> 4) * 4 + r;
      if (row < valid) {
        float* op = fout + ((long)b * T_PTS + t0 + row) * HID;
        op[wc * 32 + (lane & 15)] = acc[mt][0][r] + bcv[0];
        op[wc * 32 + 16 + (lane & 15)] = acc[mt][1][r] + bcv[1];
      }
    }
  }
}

// ---------------------------------------------------------------------------
// one-time weight pack: fp32 (K,128) -> bf16 hi/lo planes in MFMA-B-frag order
// ---------------------------------------------------------------------------
__global__ void pack_weights(const float* __restrict__ fc0,
                             const float* __restrict__ fc1,
                             const float* __restrict__ sc,
                             const float* __restrict__ fcc,
                             unsigned short* __restrict__ w0p,
                             unsigned short* __restrict__ w1p,
                             unsigned short* __restrict__ swp,
                             unsigned short* __restrict__ wcp) {
  int gid = blockIdx.x * 256 + threadIdx.x;
  const float* src;
  unsigned short* dst;
  int K, e;
  if (gid < 163840) { src = fc0; dst = w0p; K = 256; e = gid; }
  else if (gid < 327680) { src = sc; dst = swp; K = 256; e = gid - 163840; }
  else if (gid < 409600) { src = fc1; dst = w1p; K = 128; e = gid - 327680; }
  else if (gid < 425984) { src = fcc; dst = wcp; K = 128; e = gid - 409600; }
  else return;
  const int mat = e / (K * 128);
  const int r = e - mat * K * 128;
  const int k = r >> 7, n = r & 127;
  const float x = src[e];
  const unsigned short hi = bf16rne(x);
  const float hf = __uint_as_float(((unsigned)hi) << 16);
  const unsigned short lo = bf16rne(x - hf);
  const int ks = k >> 5, lg = (k >> 3) & 3, j = k & 7;
  const int l = lg * 16 + (n & 15), nt = n >> 4;
  unsigned short* mb = dst + (long)mat * K * 256;
  const int off = ((ks * 8 + nt) * 64 + l) * 8 + j;
  mb[off] = hi;
  mb[off + K * 128] = lo;
}

// --------------------------- CSR build -------------------------------------
__global__ void zero_i32(int* __restrict__ p, int n) {
  const int i = blockIdx.x * 256 + threadIdx.x;
  if (i < n) p[i] = 0;
}

__global__ void count_csr(const int* __restrict__ idx, int* __restrict__ curs) {
  const int gid = blockIdx.x * 256 + threadIdx.x;
  if (gid >= NB * T_PTS) return;
  const int b = gid / T_PTS;
  atomicAdd(&curs[b * GCELLS + idx[gid]], 1);
}

__global__ __launch_bounds__(1024) void scan_csr(const int* __restrict__ cnt,
                                                 int* __restrict__ offsets) {
  __shared__ int part[1024];
  const int t = threadIdx.x;
  const int base = t * (NCELL / 1024);
  int s = 0;
  for (int i = 0; i < NCELL / 1024; ++i) s += cnt[base + i];
  part[t] = s;
  __syncthreads();
  for (int d = 1; d < 1024; d <<= 1) {
    int v = (t >= d) ? part[t - d] : 0;
    __syncthreads();
    part[t] += v;
    __syncthreads();
  }
  int run = (t == 0) ? 0 : part[t - 1];
  for (int i = 0; i < NCELL / 1024; ++i) {
    offsets[base + i] = run;
    run += cnt[base + i];
  }
  if (t == 1023) offsets[NCELL] = run;
}

__global__ void scatter_csr(const int* __restrict__ idx,
                            const int* __restrict__ offsets,
                            int* __restrict__ curs, int* __restrict__ perm) {
  const int gid = blockIdx.x * 256 + threadIdx.x;
  if (gid >= NB * T_PTS) return;
  const int b = gid / T_PTS;
  const int cellk = b * GCELLS + idx[gid];
  const int slot = offsets[cellk] + atomicAdd(&curs[cellk], 1);
  perm[slot] = gid;
}

// ------------------- CSR segmented reductions ------------------------------
__global__ __launch_bounds__(256) void pool_csr(const unsigned* __restrict__ net,
                                                const int* __restrict__ perm,
                                                const int* __restrict__ offsets,
                                                unsigned* __restrict__ cellf) {
  const int cellk = blockIdx.x * 4 + (threadIdx.x >> 6);
  const int lane = threadIdx.x & 63;
  const int s0 = offsets[cellk], s1 = offsets[cellk + 1];
  if (s0 >= s1) return;
  float m0 = -3.402823466e38f, m1 = -3.402823466e38f;
  unsigned b0 = 0u, b1 = 0u;
  for (int j = s0; j < s1; ++j) {
    const long row = perm[j];
    uint2 w = *(const uint2*)(net + row * HID + lane * 2);
    float v0 = __uint_as_float(w.x & 0xFFFF0000u) + __uint_as_float(w.x << 16);
    float v1 = __uint_as_float(w.y & 0xFFFF0000u) + __uint_as_float(w.y << 16);
    if (v0 > m0) { m0 = v0; b0 = w.x; }
    if (v1 > m1) { m1 = v1; b1 = w.y; }
  }
  uint2 o; o.x = b0; o.y = b1;
  *(uint2*)(cellf + (long)cellk * HID + lane * 2) = o;
}

__global__ __launch_bounds__(256) void cellsum_csr(
    const float* __restrict__ c, const int* __restrict__ perm,
    const int* __restrict__ offsets, float* __restrict__ sums) {
  const int cellk = blockIdx.x * 4 + (threadIdx.x >> 6);
  const int lane = threadIdx.x & 63;
  const int s0 = offsets[cellk], s1 = offsets[cellk + 1];
  if (s0 >= s1) return;
  float2 m = {0.f, 0.f};
  for (int j = s0; j < s1; ++j) {
    const long row = perm[j];
    float2 v = *(const float2*)(c + row * HID + lane * 2);
    m.x += v.x;
    m.y += v.y;
  }
  *(float2*)(sums + (long)cellk * HID + lane * 2) = m;
}

__global__ void mean_kernel(const float* __restrict__ sums,
                            const int* __restrict__ offsets,
                            float* __restrict__ out) {
  const long gid = (long)blockIdx.x * 256 + threadIdx.x;
  if (gid >= (long)NB * HID * GCELLS) return;
  const int g = (int)(gid % GCELLS);
  const int c = (int)((gid / GCELLS) % HID);
  const int b = (int)(gid / ((long)HID * GCELLS));
  const int cellk = b * GCELLS + g;
  const int cnt = offsets[cellk + 1] - offsets[cellk];
  out[gid] = cnt > 0 ? sums[(long)cellk * HID + c] / (float)cnt : 0.f;
}

extern "C" void kernel_launch(void* const* d_in, const int* in_sizes, int n_in,
                              void* d_out, int out_size, void* d_ws,
                              size_t ws_size, hipStream_t stream) {
  const float* points = (const float*)d_in[0];
  const int* idx = (const int*)d_in[1];
  const float* fc_pos_w = (const float*)d_in[2];
  const float* fc_pos_b = (const float*)d_in[3];
  const float* fc0_w = (const float*)d_in[4];
  const float* fc0_b = (const float*)d_in[5];
  const float* fc1_w = (const float*)d_in[6];
  const float* fc1_b = (const float*)d_in[7];
  const float* sc_w = (const float*)d_in[8];
  const float* fc_c_w = (const float*)d_in[9];
  const float* fc_c_b = (const float*)d_in[10];
  float* out = (float*)d_out;

  const long NET_BYTES = (long)NB * T_PTS * HID * 4;    // 102,400,000
  const long CELL_BYTES = (long)NB * GCELLS * HID * 4;  // 33,554,432
  unsigned* net = (unsigned*)d_ws;                       // packed (h,l)
  unsigned* cellf = (unsigned*)((char*)d_ws + NET_BYTES);
  float* sums = (float*)cellf;  // reused after last pooling
  int* offsets = (int*)((char*)d_ws + NET_BYTES + CELL_BYTES);  // 65537 ints

  // scratch in d_out's dead region (overwritten by mean_kernel at the end)
  unsigned short* packs = (unsigned short*)d_out;
  unsigned short* w0p = packs;            // 5 * 65536
  unsigned short* swp = packs + 327680;   // 5 * 65536
  unsigned short* w1p = packs + 655360;   // 5 * 32768
  unsigned short* wcp = packs + 819200;   // 32768
  int* curs = (int*)((char*)d_out + (2l << 20));
  int* perm = (int*)((char*)d_out + (3l << 20));

  const int GRID_PTS = (NB * T_PTS + 255) / 256;  // 782
  const int GRID_ZERO = (NCELL + 255) / 256;      // 256
  const int GRID_CELL = NCELL / 4;                // 16384
  const int GRID_MEAN = NB * HID * GCELLS / 256;  // 32768

  pack_weights<<<1664, 256, 0, stream>>>(fc0_w, fc1_w, sc_w, fc_c_w, w0p, w1p,
                                         swp, wcp);

  zero_i32<<<GRID_ZERO, 256, 0, stream>>>(curs, NCELL);
  count_csr<<<GRID_PTS, 256, 0, stream>>>(idx, curs);
  scan_csr<<<1, 1024, 0, stream>>>(curs, offsets);
  zero_i32<<<GRID_ZERO, 256, 0, stream>>>(curs, NCELL);
  scatter_csr<<<GRID_PTS, 256, 0, stream>>>(idx, offsets, curs, perm);

  resblock_mfma<0><<<GRID_RB, 256, 0, stream>>>(
      points, fc_pos_w, fc_pos_b, nullptr, nullptr, w0p, fc0_b, w1p, fc1_b,
      swp, net);

  for (int i = 1; i < 5; ++i) {
    pool_csr<<<GRID_CELL, 256, 0, stream>>>(net, perm, offsets, cellf);
    resblock_mfma<1><<<GRID_RB, 256, 0, stream>>>(
        net, nullptr, nullptr, cellf, idx, w0p + (long)i * 65536,
        fc0_b + i * HID, w1p + (long)i * 32768, fc1_b + i * HID,
        swp + (long)i * 65536, net);
  }

  final_mfma<<<GRID_RB, 256, 0, stream>>>(net, wcp, fc_c_b);
  cellsum_csr<<<GRID_CELL, 256, 0, stream>>>((const float*)net, perm, offsets,
                                             sums);
  mean_kernel<<<GRID_MEAN, 256, 0, stream>>>(sums, offsets, out);
}